// Round 1
// baseline (1053.823 us; speedup 1.0000x reference)
//
#include <hip/hip_runtime.h>
#include <cmath>

namespace {

constexpr int kTokens = 16384;
constexpr int kD      = 7168;
constexpr int kE      = 256;
constexpr int kTopK   = 8;
constexpr float kRouteScale = 2.5f;

constexpr int BM = 32;       // token rows per block
constexpr int BK = 32;       // k-tile
constexpr int XS_STRIDE = 36;   // padded, keeps float4 reads 16B-aligned + conflict-light
constexpr int SC_STRIDE = 260;  // padded score row

// 256 threads: GEMM mapping tx=t&31 (cols 4tx..+3 and 128+4tx..+3), ty=t>>5 (rows 4ty..+3)
__global__ __launch_bounds__(256, 2)
void gate_fused(const float* __restrict__ x,
                const float* __restrict__ W,
                const float* __restrict__ bias,
                float* __restrict__ out)
{
    // GEMM staging (xs|ws) aliased with score buffer sc (used after GEMM completes)
    __shared__ float smem[BK * XS_STRIDE + BK * kE];   // 37376 B
    float (*xs)[XS_STRIDE] = reinterpret_cast<float (*)[XS_STRIDE]>(smem);
    float (*ws)[kE]        = reinterpret_cast<float (*)[kE]>(smem + BK * XS_STRIDE);
    float (*sc)[SC_STRIDE] = reinterpret_cast<float (*)[SC_STRIDE]>(smem);  // 33280 B, aliases

    const int t  = threadIdx.x;
    const int tx = t & 31;
    const int ty = t >> 5;
    const int m0 = blockIdx.x * BM;

    const int lm = t >> 3;   // x-stage: row 0..31
    const int lc = t & 7;    // x-stage: 16B chunk 0..7

    float acc[4][8];
    float cmp[4][8];
#pragma unroll
    for (int i = 0; i < 4; ++i)
#pragma unroll
        for (int j = 0; j < 8; ++j) { acc[i][j] = 0.0f; cmp[i][j] = 0.0f; }

    const float* xrow = x + (size_t)(m0 + lm) * kD;
    const float* wrow = W + (size_t)t * kD;       // thread t stages expert row t

    for (int k0 = 0; k0 < kD; k0 += BK) {
        // global -> regs (coalesced float4 for x; per-lane 16B rows for W, lines fully reused)
        float4 xv = *reinterpret_cast<const float4*>(xrow + k0 + 4 * lc);
        float4 wv[8];
#pragma unroll
        for (int i = 0; i < 8; ++i)
            wv[i] = *reinterpret_cast<const float4*>(wrow + k0 + 4 * i);

        __syncthreads();   // previous tile fully consumed before overwrite
        // x tile transposed: xs[k][m]
        xs[4 * lc + 0][lm] = xv.x;
        xs[4 * lc + 1][lm] = xv.y;
        xs[4 * lc + 2][lm] = xv.z;
        xs[4 * lc + 3][lm] = xv.w;
        // W tile transposed: ws[k][e] — store addr = k*256 + t, lanes stride-1 => conflict-free
#pragma unroll
        for (int i = 0; i < 8; ++i) {
            ws[4 * i + 0][t] = wv[i].x;
            ws[4 * i + 1][t] = wv[i].y;
            ws[4 * i + 2][t] = wv[i].z;
            ws[4 * i + 3][t] = wv[i].w;
        }
        __syncthreads();

        // per-tile partial (keeps magnitudes small), then Kahan into acc
        float p[4][8];
#pragma unroll
        for (int i = 0; i < 4; ++i)
#pragma unroll
            for (int j = 0; j < 8; ++j) p[i][j] = 0.0f;

#pragma unroll
        for (int k = 0; k < BK; ++k) {
            float a[4], b[8];
            *reinterpret_cast<float4*>(a)     = *reinterpret_cast<const float4*>(&xs[k][4 * ty]);
            *reinterpret_cast<float4*>(b)     = *reinterpret_cast<const float4*>(&ws[k][4 * tx]);
            *reinterpret_cast<float4*>(b + 4) = *reinterpret_cast<const float4*>(&ws[k][128 + 4 * tx]);
#pragma unroll
            for (int i = 0; i < 4; ++i)
#pragma unroll
                for (int j = 0; j < 8; ++j)
                    p[i][j] = fmaf(a[i], b[j], p[i][j]);
        }

        // Kahan-compensated accumulate (no muls -> safe under ffp-contract)
#pragma unroll
        for (int i = 0; i < 4; ++i)
#pragma unroll
            for (int j = 0; j < 8; ++j) {
                const float y = p[i][j] - cmp[i][j];
                const float s = acc[i][j] + y;
                cmp[i][j] = (s - acc[i][j]) - y;
                acc[i][j] = s;
            }
    }

    __syncthreads();   // GEMM LDS dead; sc aliases it from here

    // biased scores -> LDS (precise expf; selection is tie-sensitive)
#pragma unroll
    for (int i = 0; i < 4; ++i) {
        const int row = 4 * ty + i;
#pragma unroll
        for (int j = 0; j < 8; ++j) {
            const int col = (j < 4) ? (4 * tx + j) : (128 + 4 * tx + (j - 4));
            const float s = 1.0f / (1.0f + expf(-acc[i][j]));
            sc[row][col] = s + bias[col];
        }
    }
    __syncthreads();

    // top-8 per row: 8 consecutive lanes per row (same wave), iterative argmax,
    // ties -> lowest index (matches lax.top_k)
    const int rr = t >> 3;
    const int g  = t & 7;

    float cval[kTopK];
    int   cidx[kTopK];

#pragma unroll
    for (int r = 0; r < kTopK; ++r) {
        float best = -INFINITY;
        int   bi   = kE;
        const float* rowp = sc[rr] + g * 32;
#pragma unroll 8
        for (int c = 0; c < 32; ++c) {
            const float v  = rowp[c];
            const int   ci = g * 32 + c;
            if (v > best || (v == best && ci < bi)) { best = v; bi = ci; }
        }
#pragma unroll
        for (int off = 4; off > 0; off >>= 1) {
            const float ov = __shfl_xor(best, off, 8);
            const int   oi = __shfl_xor(bi,   off, 8);
            if (ov > best || (ov == best && oi < bi)) { best = ov; bi = oi; }
        }
        cval[r] = best;
        cidx[r] = bi;
        if ((bi >> 5) == g) sc[rr][bi] = -INFINITY;   // owner lane retires the winner
        __syncthreads();
    }

    if (g == 0) {
        float uw[kTopK];
        float wsum = 0.0f;
#pragma unroll
        for (int r = 0; r < kTopK; ++r) {
            uw[r] = cval[r] - bias[cidx[r]];   // recover unbiased sigmoid score
            wsum += uw[r];
        }
        const float scale = kRouteScale / wsum;
        const size_t grow = (size_t)(m0 + rr);
#pragma unroll
        for (int r = 0; r < kTopK; ++r)
            out[grow * kTopK + r] = uw[r] * scale;
        // indices chunk: written as float values (whole d_out read as the ref's fp32)
#pragma unroll
        for (int r = 0; r < kTopK; ++r)
            out[(size_t)kTokens * kTopK + grow * kTopK + r] = (float)cidx[r];
    }
}

} // namespace

extern "C" void kernel_launch(void* const* d_in, const int* in_sizes, int n_in,
                              void* d_out, int out_size, void* d_ws, size_t ws_size,
                              hipStream_t stream)
{
    const float* x    = (const float*)d_in[0];
    const float* W    = (const float*)d_in[1];
    const float* bias = (const float*)d_in[2];
    float* out = (float*)d_out;

    dim3 grid(kTokens / BM);   // 512 blocks, 2 per CU
    dim3 block(256);
    hipLaunchKernelGGL(gate_fused, grid, block, 0, stream, x, W, bias, out);
}

// Round 3
// 338.488 us; speedup vs baseline: 3.1133x; 3.1133x over previous
//
#include <hip/hip_runtime.h>
#include <cmath>

namespace {

typedef _Float16 half8 __attribute__((ext_vector_type(8)));
typedef float f32x4 __attribute__((ext_vector_type(4)));

constexpr int kTokens = 16384;
constexpr int kD      = 7168;
constexpr int kE      = 256;
constexpr int kTopK   = 8;
constexpr float kRouteScale = 2.5f;

constexpr int BM = 64;
constexpr int BK = 32;
constexpr int NT = kD / BK;              // 224 k-tiles
constexpr float kS  = 4096.0f;           // limb scale 2^12
constexpr float kS2 = 16777216.0f;       // 2^24
constexpr float kC  = 0.000244140625f;   // 2^-12 (exact)
constexpr size_t kWsTileB = 32768;       // per-ktile W image: limb0 16K + limb1 16K
constexpr size_t kWsNeed  = (size_t)NT * kWsTileB;   // 7,340,032 B

// ---------------------------------------------------------------------------
// Pre-pass: W [256][7168] f32 -> per-ktile B-fragment images, 2 scaled f16
// limbs.  Slot for expert e, k-group kg (8 k's): (e>>4)*64 + kg*16 + (e&15).
// All limb values are normal-range f16 (wl scaled by 2^12).
// ---------------------------------------------------------------------------
__global__ void wconv_kernel(const float* __restrict__ W, unsigned char* __restrict__ ws)
{
    const int e = blockIdx.x;
    const int t = threadIdx.x;            // 0..895
    const float* src = W + (size_t)e * kD + (size_t)t * 8;
    float v[8];
    *reinterpret_cast<float4*>(v)     = *reinterpret_cast<const float4*>(src);
    *reinterpret_cast<float4*>(v + 4) = *reinterpret_cast<const float4*>(src + 4);
    half8 h, l;
#pragma unroll
    for (int j = 0; j < 8; ++j) {
        _Float16 hh = (_Float16)v[j];
        h[j] = hh;
        l[j] = (_Float16)((v[j] - (float)hh) * kS);
    }
    const int kt = t >> 2;
    const int kg = t & 3;
    const size_t off = (size_t)kt * kWsTileB +
                       (size_t)(((e >> 4) << 6) + (kg << 4) + (e & 15)) * 16;
    *reinterpret_cast<half8*>(ws + off)         = h;
    *reinterpret_cast<half8*>(ws + off + 16384) = l;
}

// ---------------------------------------------------------------------------
// Main fused kernel. 512 threads = 8 waves; block tile 64x256; wave tile
// 64x32 (4 row-frags x 2 col-frags). 5 MFMAs per frag-pair per k-tile into
// 3 scale-separated accumulators.
// LDS per buffer (45056 B): B at +0 (2 limbs x 16 colfrags x 64 slots x 16B
// = 32768), A at +32768 (3 limbs x 4 rowfrags x 64 slots x 16B = 12288).
// Double-buffered: 90112 B total; epilogue reuses it as sc[64][257] f32.
// ---------------------------------------------------------------------------
__global__ __launch_bounds__(512, 2)
void gate_mfma(const float* __restrict__ x,
               const unsigned char* __restrict__ wst,
               const float* __restrict__ bias,
               float* __restrict__ out)
{
    __shared__ unsigned char lds[90112];

    const int t    = threadIdx.x;
    const int lane = t & 63;
    const int wid  = t >> 6;              // 0..7 -> 32-col group
    const int m0   = blockIdx.x * BM;

    // A staging map (threads 0..255): row am = t>>2, k-chunk akq = t&3.
    // Slot swizzle: frag*64 + kq*16 + (row ^ (kq<<2))  -> <=2-way on write+read.
    const int am  = t >> 2;
    const int akq = t & 3;
    const int ar  = am & 15;
    const int afm = am >> 4;
    const unsigned aw_off = (unsigned)(afm * 1024 + akq * 256 + ((ar ^ (akq << 2)) << 4));
    const float* xrow = x + (size_t)(m0 + am) * kD + (akq << 3);

    // fragment read offsets
    const int l15 = lane & 15;
    const int lg  = lane >> 4;
    const unsigned ard = (unsigned)(lg * 256 + ((l15 ^ (lg << 2)) << 4)); // + limb*4096 + frag*1024
    const unsigned brd = (unsigned)(lane * 16);                            // + limb*16384 + frag*1024

    f32x4 acc0[4][2], acc1[4][2], acc2[4][2];   // 3 scale levels
    f32x4 accL[4][2], cmpL[4][2];               // Kahan two-level for acc0
#pragma unroll
    for (int i = 0; i < 4; ++i)
#pragma unroll
        for (int j = 0; j < 2; ++j) {
            acc0[i][j] = f32x4{0.f,0.f,0.f,0.f};
            acc1[i][j] = f32x4{0.f,0.f,0.f,0.f};
            acc2[i][j] = f32x4{0.f,0.f,0.f,0.f};
            accL[i][j] = f32x4{0.f,0.f,0.f,0.f};
            cmpL[i][j] = f32x4{0.f,0.f,0.f,0.f};
        }

    // ---- prologue: stage tile 0 into buf 0
    {
        float4 br[4];
#pragma unroll
        for (int p = 0; p < 4; ++p)
            br[p] = *reinterpret_cast<const float4*>(wst + (size_t)p * 8192 + (size_t)t * 16);
#pragma unroll
        for (int p = 0; p < 4; ++p)
            *reinterpret_cast<float4*>(&lds[p * 8192 + t * 16]) = br[p];
        if (t < 256) {
            float av[8];
            *reinterpret_cast<float4*>(av)     = *reinterpret_cast<const float4*>(xrow);
            *reinterpret_cast<float4*>(av + 4) = *reinterpret_cast<const float4*>(xrow + 4);
            half8 h0, h1, h2;
#pragma unroll
            for (int j = 0; j < 8; ++j) {
                float v = av[j];
                _Float16 a = (_Float16)v;  float r1 = v - (float)a;
                _Float16 b = (_Float16)(r1 * kS); float r2 = r1 - (float)b * kC;
                _Float16 c = (_Float16)(r2 * kS2);
                h0[j] = a; h1[j] = b; h2[j] = c;
            }
            *reinterpret_cast<half8*>(&lds[32768 + aw_off])        = h0;
            *reinterpret_cast<half8*>(&lds[32768 + aw_off + 4096]) = h1;
            *reinterpret_cast<half8*>(&lds[32768 + aw_off + 8192]) = h2;
        }
    }
    __syncthreads();

    int buf = 0;
    for (int kt = 0; kt < NT; ++kt) {
        const bool pre = (kt + 1 < NT);
        float4 br[4];
        float  av[8];
        if (pre) {   // issue next-tile global loads early (hide HBM under MFMA)
            const unsigned char* wsrc = wst + (size_t)(kt + 1) * kWsTileB;
#pragma unroll
            for (int p = 0; p < 4; ++p)
                br[p] = *reinterpret_cast<const float4*>(wsrc + (size_t)p * 8192 + (size_t)t * 16);
            if (t < 256) {
                const float* xs = xrow + (kt + 1) * BK;
                *reinterpret_cast<float4*>(av)     = *reinterpret_cast<const float4*>(xs);
                *reinterpret_cast<float4*>(av + 4) = *reinterpret_cast<const float4*>(xs + 4);
            }
        }

        // ---- compute tile kt from buf
        {
            const unsigned Ab = (unsigned)(buf * 45056 + 32768) + ard;
            const unsigned Bb = (unsigned)(buf * 45056) + brd;
            half8 bh[2], bl[2];
#pragma unroll
            for (int j = 0; j < 2; ++j) {
                const unsigned bo = Bb + (unsigned)((wid * 2 + j) * 1024);
                bh[j] = *reinterpret_cast<const half8*>(&lds[bo]);
                bl[j] = *reinterpret_cast<const half8*>(&lds[bo + 16384]);
            }
#pragma unroll
            for (int i = 0; i < 4; ++i) {
                const unsigned ao = Ab + (unsigned)(i * 1024);
                half8 xh = *reinterpret_cast<const half8*>(&lds[ao]);
                half8 xm = *reinterpret_cast<const half8*>(&lds[ao + 4096]);
                half8 xl = *reinterpret_cast<const half8*>(&lds[ao + 8192]);
#pragma unroll
                for (int j = 0; j < 2; ++j) {
                    acc0[i][j] = __builtin_amdgcn_mfma_f32_16x16x32_f16(xh, bh[j], acc0[i][j], 0, 0, 0);
                    acc1[i][j] = __builtin_amdgcn_mfma_f32_16x16x32_f16(xm, bh[j], acc1[i][j], 0, 0, 0);
                    acc1[i][j] = __builtin_amdgcn_mfma_f32_16x16x32_f16(xh, bl[j], acc1[i][j], 0, 0, 0);
                    acc2[i][j] = __builtin_amdgcn_mfma_f32_16x16x32_f16(xl, bh[j], acc2[i][j], 0, 0, 0);
                    acc2[i][j] = __builtin_amdgcn_mfma_f32_16x16x32_f16(xm, bl[j], acc2[i][j], 0, 0, 0);
                }
            }
        }

        if (pre) {   // write next tile into the other buffer
            const int nb = buf ^ 1;
            const unsigned nbb = (unsigned)(nb * 45056);
#pragma unroll
            for (int p = 0; p < 4; ++p)
                *reinterpret_cast<float4*>(&lds[nbb + p * 8192 + t * 16]) = br[p];
            if (t < 256) {
                half8 h0, h1, h2;
#pragma unroll
                for (int j = 0; j < 8; ++j) {
                    float v = av[j];
                    _Float16 a = (_Float16)v;  float r1 = v - (float)a;
                    _Float16 b = (_Float16)(r1 * kS); float r2 = r1 - (float)b * kC;
                    _Float16 c = (_Float16)(r2 * kS2);
                    h0[j] = a; h1[j] = b; h2[j] = c;
                }
                *reinterpret_cast<half8*>(&lds[nbb + 32768 + aw_off])        = h0;
                *reinterpret_cast<half8*>(&lds[nbb + 32768 + aw_off + 4096]) = h1;
                *reinterpret_cast<half8*>(&lds[nbb + 32768 + aw_off + 8192]) = h2;
            }
        }

        if ((kt & 15) == 15) {   // Kahan two-level spill of acc0 (bounds fp32 chain error)
#pragma unroll
            for (int i = 0; i < 4; ++i)
#pragma unroll
                for (int j = 0; j < 2; ++j) {
                    f32x4 y = acc0[i][j] - cmpL[i][j];
                    f32x4 s = accL[i][j] + y;
                    cmpL[i][j] = (s - accL[i][j]) - y;
                    accL[i][j] = s;
                    acc0[i][j] = f32x4{0.f,0.f,0.f,0.f};
                }
        }
        __syncthreads();
        buf ^= 1;
    }

    // ---- epilogue: combine limb levels, biased scores -> LDS
    float (*sc)[257] = reinterpret_cast<float (*)[257]>(lds);   // 65792 B, aliases GEMM bufs
#pragma unroll
    for (int j = 0; j < 2; ++j) {
        const int col  = wid * 32 + j * 16 + l15;
        const float bv = bias[col];
#pragma unroll
        for (int i = 0; i < 4; ++i) {
            f32x4 z = accL[i][j] + kC * (acc1[i][j] + kC * acc2[i][j]);
#pragma unroll
            for (int r = 0; r < 4; ++r) {
                const int row = i * 16 + lg * 4 + r;
                const float s = 1.0f / (1.0f + expf(-z[r]));
                sc[row][col] = s + bv;
            }
        }
    }
    __syncthreads();

    // ---- top-8 per row: 8 lanes/row, iterative argmax, ties -> lowest index
    const int rr = t >> 3;
    const int g  = t & 7;

    float cval[kTopK];
    int   cidx[kTopK];

#pragma unroll
    for (int r = 0; r < kTopK; ++r) {
        float best = -INFINITY;
        int   bi   = kE;
        const float* rowp = sc[rr] + g * 32;
#pragma unroll 8
        for (int c = 0; c < 32; ++c) {
            const float v  = rowp[c];
            const int   ci = g * 32 + c;
            if (v > best || (v == best && ci < bi)) { best = v; bi = ci; }
        }
#pragma unroll
        for (int off = 4; off > 0; off >>= 1) {
            const float ov = __shfl_xor(best, off, 8);
            const int   oi = __shfl_xor(bi,   off, 8);
            if (ov > best || (ov == best && oi < bi)) { best = ov; bi = oi; }
        }
        cval[r] = best;
        cidx[r] = bi;
        if ((bi >> 5) == g) sc[rr][bi] = -INFINITY;   // owner lane retires winner
        __syncthreads();
    }

    if (g == 0) {
        float uw[kTopK];
        float wsum = 0.0f;
#pragma unroll
        for (int r = 0; r < kTopK; ++r) {
            uw[r] = cval[r] - bias[cidx[r]];   // recover unbiased sigmoid score
            wsum += uw[r];
        }
        const float scale = kRouteScale / wsum;
        const size_t grow = (size_t)(m0 + rr);
#pragma unroll
        for (int r = 0; r < kTopK; ++r)
            out[grow * kTopK + r] = uw[r] * scale;
#pragma unroll
        for (int r = 0; r < kTopK; ++r)
            out[(size_t)kTokens * kTopK + grow * kTopK + r] = (float)cidx[r];
    }
}

// ---------------------------------------------------------------------------
// Fallback (round-1 fp32 kernel, known-good) if ws is too small.
// ---------------------------------------------------------------------------
constexpr int FBM = 32;
constexpr int FBK = 32;
constexpr int XS_STRIDE = 36;
constexpr int SC_STRIDE = 260;

__global__ __launch_bounds__(256, 2)
void gate_fused(const float* __restrict__ x,
                const float* __restrict__ W,
                const float* __restrict__ bias,
                float* __restrict__ out)
{
    __shared__ float smem[FBK * XS_STRIDE + FBK * kE];
    float (*xs)[XS_STRIDE] = reinterpret_cast<float (*)[XS_STRIDE]>(smem);
    float (*ws)[kE]        = reinterpret_cast<float (*)[kE]>(smem + FBK * XS_STRIDE);
    float (*sc)[SC_STRIDE] = reinterpret_cast<float (*)[SC_STRIDE]>(smem);

    const int t  = threadIdx.x;
    const int tx = t & 31;
    const int ty = t >> 5;
    const int m0 = blockIdx.x * FBM;
    const int lm = t >> 3;
    const int lc = t & 7;

    float acc[4][8];
    float cmp[4][8];
#pragma unroll
    for (int i = 0; i < 4; ++i)
#pragma unroll
        for (int j = 0; j < 8; ++j) { acc[i][j] = 0.0f; cmp[i][j] = 0.0f; }

    const float* xrow = x + (size_t)(m0 + lm) * kD;
    const float* wrow = W + (size_t)t * kD;

    for (int k0 = 0; k0 < kD; k0 += FBK) {
        float4 xv = *reinterpret_cast<const float4*>(xrow + k0 + 4 * lc);
        float4 wv[8];
#pragma unroll
        for (int i = 0; i < 8; ++i)
            wv[i] = *reinterpret_cast<const float4*>(wrow + k0 + 4 * i);
        __syncthreads();
        xs[4 * lc + 0][lm] = xv.x; xs[4 * lc + 1][lm] = xv.y;
        xs[4 * lc + 2][lm] = xv.z; xs[4 * lc + 3][lm] = xv.w;
#pragma unroll
        for (int i = 0; i < 8; ++i) {
            ws[4 * i + 0][t] = wv[i].x; ws[4 * i + 1][t] = wv[i].y;
            ws[4 * i + 2][t] = wv[i].z; ws[4 * i + 3][t] = wv[i].w;
        }
        __syncthreads();
        float p[4][8];
#pragma unroll
        for (int i = 0; i < 4; ++i)
#pragma unroll
            for (int j = 0; j < 8; ++j) p[i][j] = 0.0f;
#pragma unroll
        for (int k = 0; k < FBK; ++k) {
            float a[4], b[8];
            *reinterpret_cast<float4*>(a)     = *reinterpret_cast<const float4*>(&xs[k][4 * ty]);
            *reinterpret_cast<float4*>(b)     = *reinterpret_cast<const float4*>(&ws[k][4 * tx]);
            *reinterpret_cast<float4*>(b + 4) = *reinterpret_cast<const float4*>(&ws[k][128 + 4 * tx]);
#pragma unroll
            for (int i = 0; i < 4; ++i)
#pragma unroll
                for (int j = 0; j < 8; ++j)
                    p[i][j] = fmaf(a[i], b[j], p[i][j]);
        }
#pragma unroll
        for (int i = 0; i < 4; ++i)
#pragma unroll
            for (int j = 0; j < 8; ++j) {
                const float y = p[i][j] - cmp[i][j];
                const float s = acc[i][j] + y;
                cmp[i][j] = (s - acc[i][j]) - y;
                acc[i][j] = s;
            }
    }
    __syncthreads();
#pragma unroll
    for (int i = 0; i < 4; ++i) {
        const int row = 4 * ty + i;
#pragma unroll
        for (int j = 0; j < 8; ++j) {
            const int col = (j < 4) ? (4 * tx + j) : (128 + 4 * tx + (j - 4));
            const float s = 1.0f / (1.0f + expf(-acc[i][j]));
            sc[row][col] = s + bias[col];
        }
    }
    __syncthreads();
    const int rr = t >> 3;
    const int g  = t & 7;
    float cval[kTopK];
    int   cidx[kTopK];
#pragma unroll
    for (int r = 0; r < kTopK; ++r) {
        float best = -INFINITY;
        int   bi   = kE;
        const float* rowp = sc[rr] + g * 32;
#pragma unroll 8
        for (int c = 0; c < 32; ++c) {
            const float v  = rowp[c];
            const int   ci = g * 32 + c;
            if (v > best || (v == best && ci < bi)) { best = v; bi = ci; }
        }
#pragma unroll
        for (int off = 4; off > 0; off >>= 1) {
            const float ov = __shfl_xor(best, off, 8);
            const int   oi = __shfl_xor(bi,   off, 8);
            if (ov > best || (ov == best && oi < bi)) { best = ov; bi = oi; }
        }
        cval[r] = best; cidx[r] = bi;
        if ((bi >> 5) == g) sc[rr][bi] = -INFINITY;
        __syncthreads();
    }
    if (g == 0) {
        float uw[kTopK];
        float wsum = 0.0f;
#pragma unroll
        for (int r = 0; r < kTopK; ++r) { uw[r] = cval[r] - bias[cidx[r]]; wsum += uw[r]; }
        const float scale = kRouteScale / wsum;
        const size_t grow = (size_t)(m0 + rr);
#pragma unroll
        for (int r = 0; r < kTopK; ++r) out[grow * kTopK + r] = uw[r] * scale;
#pragma unroll
        for (int r = 0; r < kTopK; ++r)
            out[(size_t)kTokens * kTopK + grow * kTopK + r] = (float)cidx[r];
    }
}

} // namespace

extern "C" void kernel_launch(void* const* d_in, const int* in_sizes, int n_in,
                              void* d_out, int out_size, void* d_ws, size_t ws_size,
                              hipStream_t stream)
{
    const float* x    = (const float*)d_in[0];
    const float* W    = (const float*)d_in[1];
    const float* bias = (const float*)d_in[2];
    float* out = (float*)d_out;

    if (ws_size >= kWsNeed) {
        unsigned char* ws = (unsigned char*)d_ws;
        hipLaunchKernelGGL(wconv_kernel, dim3(kE), dim3(kD / 8), 0, stream, W, ws);
        hipLaunchKernelGGL(gate_mfma, dim3(kTokens / BM), dim3(512), 0, stream, x, ws, bias, out);
    } else {
        hipLaunchKernelGGL(gate_fused, dim3(kTokens / FBM), dim3(256), 0, stream, x, W, bias, out);
    }
}